// Round 1
// baseline (2248.882 us; speedup 1.0000x reference)
//
#include <hip/hip_runtime.h>

#define HID 128
#define TE  64
#define LDP 132   // padded LDS row stride (floats): 132%32=4 -> 2-way conflicts max (free)

__device__ __forceinline__ float silu_f(float x) {
    return x * (1.0f / (1.0f + __expf(-x)));
}

__device__ __forceinline__ void load8(float* w, const float* __restrict__ p) {
    float4 a = *(const float4*)p;
    float4 b = *(const float4*)(p + 4);
    w[0] = a.x; w[1] = a.y; w[2] = a.z; w[3] = a.w;
    w[4] = b.x; w[5] = b.y; w[6] = b.z; w[7] = b.w;
}

// acc[4 edges][8 feats] += s_in[eB..eB+3][0..127] @ W[0..127][n0..n0+7]
__device__ __forceinline__ void gemm_lds(float acc_[4][8], const float (*s_in)[LDP],
                                         int eB, int n0, const float* __restrict__ W)
{
    for (int k = 0; k < HID; k += 4) {
        float a[4][4];
        #pragma unroll
        for (int i = 0; i < 4; ++i) {
            float4 v = *(const float4*)&s_in[eB + i][k];
            a[i][0] = v.x; a[i][1] = v.y; a[i][2] = v.z; a[i][3] = v.w;
        }
        #pragma unroll
        for (int kk = 0; kk < 4; ++kk) {
            float w[8];
            load8(w, W + (size_t)(k + kk) * HID + n0);
            #pragma unroll
            for (int i = 0; i < 4; ++i)
                #pragma unroll
                for (int j = 0; j < 8; ++j)
                    acc_[i][j] = fmaf(a[i][kk], w[j], acc_[i][j]);
        }
    }
}

// acc[4][8] += rows er[i][0..127] @ W[0..127][n0..n0+7]  (global-gathered rows)
__device__ __forceinline__ void gemm_glb(float acc_[4][8], const float* const* er,
                                         int n0, const float* __restrict__ W)
{
    for (int k = 0; k < HID; k += 4) {
        float a[4][4];
        #pragma unroll
        for (int i = 0; i < 4; ++i) {
            float4 v = *(const float4*)(er[i] + k);
            a[i][0] = v.x; a[i][1] = v.y; a[i][2] = v.z; a[i][3] = v.w;
        }
        #pragma unroll
        for (int kk = 0; kk < 4; ++kk) {
            float w[8];
            load8(w, W + (size_t)(k + kk) * HID + n0);
            #pragma unroll
            for (int i = 0; i < 4; ++i)
                #pragma unroll
                for (int j = 0; j < 8; ++j)
                    acc_[i][j] = fmaf(a[i][kk], w[j], acc_[i][j]);
        }
    }
}

extern "C" __global__ void __launch_bounds__(256, 2)
edge_kernel(const float* __restrict__ emb,
            const float* __restrict__ npos,
            const float* __restrict__ gpos,
            const int* __restrict__ ei,     // [2,E] int32
            const float* __restrict__ ew1, const float* __restrict__ eb1,
            const float* __restrict__ ew2, const float* __restrict__ eb2,
            const float* __restrict__ mw1, const float* __restrict__ mb1,
            const float* __restrict__ mw2, const float* __restrict__ mb2,
            float* __restrict__ sums,       // [G,HID] accumulators (d_out)
            float* __restrict__ counts,     // [G]
            int E)
{
    __shared__ float s_x[TE][LDP];
    __shared__ float s_y[TE][LDP];
    __shared__ float s_attr[TE][6];
    __shared__ int   s_ii[TE];
    __shared__ int   s_jj[TE];

    const int t  = threadIdx.x;
    const int e0 = blockIdx.x * TE;

    if (t < TE) {
        int e = e0 + t;
        int i = ei[e];
        int j = ei[E + e];
        s_ii[t] = i;
        s_jj[t] = j;
        const float* np = npos + (size_t)i * 3;
        const float* gp = gpos + (size_t)j * 3;
        s_attr[t][0] = np[0]; s_attr[t][1] = np[1]; s_attr[t][2] = np[2];
        s_attr[t][3] = gp[0]; s_attr[t][4] = gp[1]; s_attr[t][5] = gp[2];
        atomicAdd(&counts[j], 1.0f);
    }
    __syncthreads();

    const int fe = t & 15;    // 16 feature groups of 8
    const int eg = t >> 4;    // 16 edge groups of 4
    const int n0 = fe * 8;
    const int eB = eg * 4;

    float acc_[4][8];

    // ---- Layer 1: h1 = silu(attr @ ew1 + eb1) -> s_x   (K=6)
    {
        #pragma unroll
        for (int i = 0; i < 4; ++i)
            #pragma unroll
            for (int j = 0; j < 8; ++j) acc_[i][j] = 0.0f;

        #pragma unroll
        for (int k = 0; k < 6; ++k) {
            float w[8];
            load8(w, ew1 + (size_t)k * HID + n0);
            #pragma unroll
            for (int i = 0; i < 4; ++i) {
                float a = s_attr[eB + i][k];
                #pragma unroll
                for (int j = 0; j < 8; ++j)
                    acc_[i][j] = fmaf(a, w[j], acc_[i][j]);
            }
        }
        float b[8];
        load8(b, eb1 + n0);
        #pragma unroll
        for (int i = 0; i < 4; ++i)
            #pragma unroll
            for (int j = 0; j < 8; ++j)
                s_x[eB + i][n0 + j] = silu_f(acc_[i][j] + b[j]);
    }
    __syncthreads();

    // ---- Layer 2: pos_emb = h1 @ ew2 + eb2 -> s_y   (K=128, no act)
    {
        #pragma unroll
        for (int i = 0; i < 4; ++i)
            #pragma unroll
            for (int j = 0; j < 8; ++j) acc_[i][j] = 0.0f;
        gemm_lds(acc_, s_x, eB, n0, ew2);
        float b[8];
        load8(b, eb2 + n0);
        #pragma unroll
        for (int i = 0; i < 4; ++i)
            #pragma unroll
            for (int j = 0; j < 8; ++j)
                s_y[eB + i][n0 + j] = acc_[i][j] + b[j];
    }
    __syncthreads();

    // ---- Layer 3: h2 = silu(emb @ mw1[:128] + pos_emb @ mw1[128:] + mb1) -> s_x
    {
        const float* erow[4];
        #pragma unroll
        for (int i = 0; i < 4; ++i)
            erow[i] = emb + (size_t)s_ii[eB + i] * HID;

        #pragma unroll
        for (int i = 0; i < 4; ++i)
            #pragma unroll
            for (int j = 0; j < 8; ++j) acc_[i][j] = 0.0f;
        gemm_glb(acc_, erow, n0, mw1);
        gemm_lds(acc_, s_y, eB, n0, mw1 + (size_t)HID * HID);
        float b[8];
        load8(b, mb1 + n0);
        #pragma unroll
        for (int i = 0; i < 4; ++i)
            #pragma unroll
            for (int j = 0; j < 8; ++j)
                s_x[eB + i][n0 + j] = silu_f(acc_[i][j] + b[j]);
    }
    __syncthreads();

    // ---- Layer 4: message = h2 @ mw2 + mb2 -> atomicAdd into sums[j]
    {
        #pragma unroll
        for (int i = 0; i < 4; ++i)
            #pragma unroll
            for (int j = 0; j < 8; ++j) acc_[i][j] = 0.0f;
        gemm_lds(acc_, s_x, eB, n0, mw2);
        float b[8];
        load8(b, mb2 + n0);
        #pragma unroll
        for (int i = 0; i < 4; ++i) {
            float* dst = sums + (size_t)s_jj[eB + i] * HID + n0;
            #pragma unroll
            for (int j = 0; j < 8; ++j)
                atomicAdd(dst + j, acc_[i][j] + b[j]);
        }
    }
}

extern "C" __global__ void __launch_bounds__(256, 2)
update_kernel(const float* __restrict__ uw1, const float* __restrict__ ub1,
              const float* __restrict__ uw2, const float* __restrict__ ub2,
              const float* __restrict__ counts,
              float* __restrict__ out,   // in: sums, out: update  [G,HID]
              int G)
{
    __shared__ float s_x[TE][LDP];
    __shared__ float s_y[TE][LDP];

    const int t  = threadIdx.x;
    const int c0 = blockIdx.x * TE;

    // load mean: 4 threads per cell, 32 floats each
    {
        int c    = t >> 2;
        int part = t & 3;
        float r = 1.0f / counts[c0 + c];
        const float4* src = (const float4*)(out + (size_t)(c0 + c) * HID + part * 32);
        #pragma unroll
        for (int q = 0; q < 8; ++q) {
            float4 v = src[q];
            v.x *= r; v.y *= r; v.z *= r; v.w *= r;
            *(float4*)&s_x[c][part * 32 + q * 4] = v;
        }
    }
    __syncthreads();

    const int fe = t & 15;
    const int eg = t >> 4;
    const int n0 = fe * 8;
    const int eB = eg * 4;

    float acc_[4][8];

    // u1: silu(mean @ uw1 + ub1) -> s_y
    {
        #pragma unroll
        for (int i = 0; i < 4; ++i)
            #pragma unroll
            for (int j = 0; j < 8; ++j) acc_[i][j] = 0.0f;
        gemm_lds(acc_, s_x, eB, n0, uw1);
        float b[8];
        load8(b, ub1 + n0);
        #pragma unroll
        for (int i = 0; i < 4; ++i)
            #pragma unroll
            for (int j = 0; j < 8; ++j)
                s_y[eB + i][n0 + j] = silu_f(acc_[i][j] + b[j]);
    }
    __syncthreads();

    // u2: update = h @ uw2 + ub2 -> out
    {
        #pragma unroll
        for (int i = 0; i < 4; ++i)
            #pragma unroll
            for (int j = 0; j < 8; ++j) acc_[i][j] = 0.0f;
        gemm_lds(acc_, s_y, eB, n0, uw2);
        float b[8];
        load8(b, ub2 + n0);
        #pragma unroll
        for (int i = 0; i < 4; ++i) {
            float* dst = out + (size_t)(c0 + eB + i) * HID + n0;
            float2 v0 = make_float2(acc_[i][0] + b[0], acc_[i][1] + b[1]);
            float2 v1 = make_float2(acc_[i][2] + b[2], acc_[i][3] + b[3]);
            float2 v2 = make_float2(acc_[i][4] + b[4], acc_[i][5] + b[5]);
            float2 v3 = make_float2(acc_[i][6] + b[6], acc_[i][7] + b[7]);
            *(float2*)(dst + 0) = v0;
            *(float2*)(dst + 2) = v1;
            *(float2*)(dst + 4) = v2;
            *(float2*)(dst + 6) = v3;
        }
    }
}

extern "C" void kernel_launch(void* const* d_in, const int* in_sizes, int n_in,
                              void* d_out, int out_size, void* d_ws, size_t ws_size,
                              hipStream_t stream)
{
    const float* emb  = (const float*)d_in[0];
    const float* npos = (const float*)d_in[1];
    const float* gpos = (const float*)d_in[2];
    const int*   ei   = (const int*)d_in[3];
    const float* ew1  = (const float*)d_in[4];
    const float* eb1  = (const float*)d_in[5];
    const float* ew2  = (const float*)d_in[6];
    const float* eb2  = (const float*)d_in[7];
    const float* mw1  = (const float*)d_in[8];
    const float* mb1  = (const float*)d_in[9];
    const float* mw2  = (const float*)d_in[10];
    const float* mb2  = (const float*)d_in[11];
    const float* uw1  = (const float*)d_in[12];
    const float* ub1  = (const float*)d_in[13];
    const float* uw2  = (const float*)d_in[14];
    const float* ub2  = (const float*)d_in[15];

    const int E = in_sizes[3] / 2;
    const int G = in_sizes[2] / 3;

    float* sums   = (float*)d_out;   // [G, HID] accumulators, overwritten by update
    float* counts = (float*)d_ws;    // [G]

    hipMemsetAsync(d_out, 0, (size_t)out_size * sizeof(float), stream);
    hipMemsetAsync(d_ws, 0, (size_t)G * sizeof(float), stream);

    edge_kernel<<<E / TE, 256, 0, stream>>>(emb, npos, gpos, ei,
                                            ew1, eb1, ew2, eb2,
                                            mw1, mb1, mw2, mb2,
                                            sums, counts, E);
    update_kernel<<<G / TE, 256, 0, stream>>>(uw1, ub1, uw2, ub2, counts, sums, G);
}

// Round 2
// 324.960 us; speedup vs baseline: 6.9205x; 6.9205x over previous
//
#include <hip/hip_runtime.h>

#define HID 128
#define TE  64     // edges (or cells) per block
#define LDK 136    // bf16 LDS row stride for 128-wide buffers (272B -> 2-way max, free)
#define LDA 40     // bf16 LDS row stride for 32-wide attr buffer (80B -> 2-way max)

// bf16 weight region offsets (in bf16 elements) inside d_ws after counts
#define WT_E1 0
#define WT_E2 4096
#define WT_M1 20480
#define WT_M2 53248
#define WT_U1 69632
#define WT_U2 86016
#define WT_TOTAL 102400

typedef __attribute__((ext_vector_type(8))) short bf16x8;
typedef __attribute__((ext_vector_type(4))) float f32x4;

#define MFMA(a, b, c) __builtin_amdgcn_mfma_f32_16x16x32_bf16(a, b, c, 0, 0, 0)

__device__ __forceinline__ float silu_f(float x) {
    return x * (1.0f / (1.0f + __expf(-x)));
}

// fp32 -> bf16 (round-to-nearest-even), as raw short
__device__ __forceinline__ short f2b(float x) {
    union { float f; unsigned u; } v; v.f = x;
    unsigned r = v.u + 0x7fff + ((v.u >> 16) & 1);
    return (short)(r >> 16);
}

// ---------------------------------------------------------------------------
// Weight conversion: fp32 row-major W[k][n] -> bf16 transposed Wt[n][k]
// ---------------------------------------------------------------------------
extern "C" __global__ void __launch_bounds__(256)
convert_w(const float* __restrict__ ew1, const float* __restrict__ ew2,
          const float* __restrict__ mw1, const float* __restrict__ mw2,
          const float* __restrict__ uw1, const float* __restrict__ uw2,
          short* __restrict__ wt)
{
    int idx = blockIdx.x * 256 + threadIdx.x;
    if (idx >= WT_TOTAL) return;
    int r = idx;
    if (r < 4096) {                               // ew1: [6][128] -> [128][32] K-padded
        int n = r >> 5, k = r & 31;
        wt[idx] = f2b(k < 6 ? ew1[k * HID + n] : 0.0f);
        return;
    }
    r -= 4096;
    if (r < 16384) { int n = r >> 7, k = r & 127; wt[idx] = f2b(ew2[k * HID + n]); return; }
    r -= 16384;
    if (r < 32768) { int n = r >> 8, k = r & 255; wt[idx] = f2b(mw1[k * HID + n]); return; }
    r -= 32768;
    if (r < 16384) { int n = r >> 7, k = r & 127; wt[idx] = f2b(mw2[k * HID + n]); return; }
    r -= 16384;
    if (r < 16384) { int n = r >> 7, k = r & 127; wt[idx] = f2b(uw1[k * HID + n]); return; }
    r -= 16384;
    { int n = r >> 7, k = r & 127; wt[idx] = f2b(uw2[k * HID + n]); return; }
}

// ---------------------------------------------------------------------------
// Shared GEMM building blocks.
//  A-frag: lane holds row (lane&15) of its 16-row M-frag, k-chunk (lane>>4)*8
//  B-frag: lane holds col (lane&15) (= row of Wt), k-chunk (lane>>4)*8
//  C-frag: col = lane&15, row = (lane>>4)*4 + reg
// ---------------------------------------------------------------------------

// acc[4][2] += A(64 x 32*KSTEPS from LDS, k offset kA0) @ Wt(cols nb..nb+31, k offset kB0)
__device__ __forceinline__ void gemm_tile(f32x4 acc[4][2],
                                          const short* __restrict__ sA, int ldsa, int kA0,
                                          const short* __restrict__ wtB, int ldb, int kB0,
                                          int ksteps, int q, int h, int nb)
{
    for (int ks = 0; ks < ksteps; ++ks) {
        int kb = kB0 + ks * 32 + h * 8;
        bf16x8 b0 = *(const bf16x8*)(wtB + (size_t)(nb + q) * ldb + kb);
        bf16x8 b1 = *(const bf16x8*)(wtB + (size_t)(nb + 16 + q) * ldb + kb);
        int ka = kA0 + ks * 32 + h * 8;
        #pragma unroll
        for (int m = 0; m < 4; ++m) {
            bf16x8 a = *(const bf16x8*)(sA + (m * 16 + q) * ldsa + ka);
            acc[m][0] = MFMA(a, b0, acc[m][0]);
            acc[m][1] = MFMA(a, b1, acc[m][1]);
        }
    }
}

// bias + (optional silu) -> bf16 -> LDS[row][n]
__device__ __forceinline__ void epi_lds(f32x4 acc[4][2], const float* __restrict__ bias,
                                        short* __restrict__ sOut, int q, int h, int nb,
                                        bool act)
{
    #pragma unroll
    for (int nf = 0; nf < 2; ++nf) {
        int n = nb + nf * 16 + q;
        float bb = bias[n];
        #pragma unroll
        for (int m = 0; m < 4; ++m) {
            f32x4 v = acc[m][nf];
            #pragma unroll
            for (int r = 0; r < 4; ++r) {
                float z = v[r] + bb;
                if (act) z = silu_f(z);
                sOut[(m * 16 + h * 4 + r) * LDK + n] = f2b(z);
            }
        }
    }
}

__device__ __forceinline__ void zero_acc(f32x4 acc[4][2]) {
    #pragma unroll
    for (int m = 0; m < 4; ++m)
        #pragma unroll
        for (int nf = 0; nf < 2; ++nf)
            acc[m][nf] = (f32x4)(0.0f);
}

// ---------------------------------------------------------------------------
// Edge kernel: 64 edges/block, 256 threads = 4 waves, wave owns 32 output cols
// ---------------------------------------------------------------------------
extern "C" __global__ void __launch_bounds__(256, 3)
edge_kernel(const float* __restrict__ emb,
            const float* __restrict__ npos,
            const float* __restrict__ gpos,
            const int* __restrict__ ei,
            const float* __restrict__ eb1, const float* __restrict__ eb2,
            const float* __restrict__ mb1, const float* __restrict__ mb2,
            const short* __restrict__ wt,
            float* __restrict__ sums,
            float* __restrict__ counts,
            int E)
{
    __shared__ short s_e[TE * LDK];   // gathered node embedding (bf16)
    __shared__ short s_x[TE * LDK];   // h1 / h2 ping
    __shared__ short s_y[TE * LDK];   // attr (overlaid) then pos_emb
    __shared__ int   s_jj[TE];

    const int t  = threadIdx.x;
    const int e0 = blockIdx.x * TE;

    // ---- stage 0a: attr (K-padded to 32, bf16) + dest ids + counts
    if (t < TE) {
        int e = e0 + t;
        int i = ei[e];
        int j = ei[E + e];
        s_jj[t] = j;
        const float* np = npos + (size_t)i * 3;
        const float* gp = gpos + (size_t)j * 3;
        short* arow = s_y + t * LDA;   // attr overlaid on s_y (dead after layer 1)
        arow[0] = f2b(np[0]); arow[1] = f2b(np[1]); arow[2] = f2b(np[2]);
        arow[3] = f2b(gp[0]); arow[4] = f2b(gp[1]); arow[5] = f2b(gp[2]);
        #pragma unroll
        for (int k = 6; k < 32; ++k) arow[k] = 0;
        atomicAdd(&counts[j], 1.0f);
    }

    // ---- stage 0b: gather node embedding -> bf16 LDS (all 256 threads)
    {
        int e    = t >> 2;
        int part = t & 3;
        int i    = ei[e0 + e];                       // 4 threads read same -> cached
        const float4* src = (const float4*)(emb + (size_t)i * HID + part * 32);
        short* dst = s_e + e * LDK + part * 32;
        #pragma unroll
        for (int qd = 0; qd < 8; ++qd) {
            float4 v = src[qd];
            short4 b;
            b.x = f2b(v.x); b.y = f2b(v.y); b.z = f2b(v.z); b.w = f2b(v.w);
            *(short4*)(dst + qd * 4) = b;
        }
    }
    __syncthreads();

    const int lane = t & 63;
    const int q = lane & 15;
    const int h = lane >> 4;
    const int nb = (t >> 6) * 32;

    f32x4 acc[4][2];

    // ---- L1: h1 = silu(attr @ ew1 + eb1) -> s_x   (K=32 padded)
    zero_acc(acc);
    gemm_tile(acc, s_y, LDA, 0, wt + WT_E1, 32, 0, 1, q, h, nb);
    epi_lds(acc, eb1, s_x, q, h, nb, true);
    __syncthreads();

    // ---- L2: pos = h1 @ ew2 + eb2 -> s_y
    zero_acc(acc);
    gemm_tile(acc, s_x, LDK, 0, wt + WT_E2, HID, 0, 4, q, h, nb);
    epi_lds(acc, eb2, s_y, q, h, nb, false);
    __syncthreads();

    // ---- L3: h2 = silu(emb @ mw1[:128] + pos @ mw1[128:] + mb1) -> s_x
    zero_acc(acc);
    gemm_tile(acc, s_e, LDK, 0, wt + WT_M1, 256, 0,   4, q, h, nb);
    gemm_tile(acc, s_y, LDK, 0, wt + WT_M1, 256, 128, 4, q, h, nb);
    epi_lds(acc, mb1, s_x, q, h, nb, true);
    __syncthreads();

    // ---- L4: message = h2 @ mw2 + mb2 -> atomic scatter into sums[j]
    zero_acc(acc);
    gemm_tile(acc, s_x, LDK, 0, wt + WT_M2, HID, 0, 4, q, h, nb);
    #pragma unroll
    for (int nf = 0; nf < 2; ++nf) {
        int n = nb + nf * 16 + q;
        float bb = mb2[n];
        #pragma unroll
        for (int m = 0; m < 4; ++m) {
            f32x4 v = acc[m][nf];
            #pragma unroll
            for (int r = 0; r < 4; ++r) {
                int row = m * 16 + h * 4 + r;
                atomicAdd(sums + (size_t)s_jj[row] * HID + n, v[r] + bb);
            }
        }
    }
}

// ---------------------------------------------------------------------------
// Update kernel: 64 cells/block; mean -> silu MLP -> out (in-place over sums)
// ---------------------------------------------------------------------------
extern "C" __global__ void __launch_bounds__(256, 3)
update_kernel(const float* __restrict__ ub1, const float* __restrict__ ub2,
              const short* __restrict__ wt,
              const float* __restrict__ counts,
              float* __restrict__ out, int G)
{
    __shared__ short s_x[TE * LDK];
    __shared__ short s_y[TE * LDK];

    const int t  = threadIdx.x;
    const int c0 = blockIdx.x * TE;

    // stage: mean = sums / count -> bf16 LDS
    {
        int c    = t >> 2;
        int part = t & 3;
        float rc = 1.0f / counts[c0 + c];
        const float4* src = (const float4*)(out + (size_t)(c0 + c) * HID + part * 32);
        short* dst = s_x + c * LDK + part * 32;
        #pragma unroll
        for (int qd = 0; qd < 8; ++qd) {
            float4 v = src[qd];
            short4 b;
            b.x = f2b(v.x * rc); b.y = f2b(v.y * rc);
            b.z = f2b(v.z * rc); b.w = f2b(v.w * rc);
            *(short4*)(dst + qd * 4) = b;
        }
    }
    __syncthreads();

    const int lane = t & 63;
    const int q = lane & 15;
    const int h = lane >> 4;
    const int nb = (t >> 6) * 32;

    f32x4 acc[4][2];

    // u1: silu(mean @ uw1 + ub1) -> s_y
    zero_acc(acc);
    gemm_tile(acc, s_x, LDK, 0, wt + WT_U1, HID, 0, 4, q, h, nb);
    epi_lds(acc, ub1, s_y, q, h, nb, true);
    __syncthreads();

    // u2: out = h @ uw2 + ub2
    zero_acc(acc);
    gemm_tile(acc, s_y, LDK, 0, wt + WT_U2, HID, 0, 4, q, h, nb);
    #pragma unroll
    for (int nf = 0; nf < 2; ++nf) {
        int n = nb + nf * 16 + q;
        float bb = ub2[n];
        #pragma unroll
        for (int m = 0; m < 4; ++m) {
            f32x4 v = acc[m][nf];
            #pragma unroll
            for (int r = 0; r < 4; ++r) {
                int row = c0 + m * 16 + h * 4 + r;
                out[(size_t)row * HID + n] = v[r] + bb;
            }
        }
    }
}

// ---------------------------------------------------------------------------
extern "C" void kernel_launch(void* const* d_in, const int* in_sizes, int n_in,
                              void* d_out, int out_size, void* d_ws, size_t ws_size,
                              hipStream_t stream)
{
    const float* emb  = (const float*)d_in[0];
    const float* npos = (const float*)d_in[1];
    const float* gpos = (const float*)d_in[2];
    const int*   ei   = (const int*)d_in[3];
    const float* ew1  = (const float*)d_in[4];
    const float* eb1  = (const float*)d_in[5];
    const float* ew2  = (const float*)d_in[6];
    const float* eb2  = (const float*)d_in[7];
    const float* mw1  = (const float*)d_in[8];
    const float* mb1  = (const float*)d_in[9];
    const float* mw2  = (const float*)d_in[10];
    const float* mb2  = (const float*)d_in[11];
    const float* uw1  = (const float*)d_in[12];
    const float* ub1  = (const float*)d_in[13];
    const float* uw2  = (const float*)d_in[14];
    const float* ub2  = (const float*)d_in[15];

    const int E = in_sizes[3] / 2;
    const int G = in_sizes[2] / 3;

    float* sums   = (float*)d_out;                       // [G, HID]
    float* counts = (float*)d_ws;                        // [G]
    short* wt     = (short*)((char*)d_ws + (size_t)G * sizeof(float));

    hipMemsetAsync(d_out, 0, (size_t)out_size * sizeof(float), stream);
    hipMemsetAsync(d_ws, 0, (size_t)G * sizeof(float), stream);

    convert_w<<<(WT_TOTAL + 255) / 256, 256, 0, stream>>>(ew1, ew2, mw1, mw2, uw1, uw2, wt);
    edge_kernel<<<E / TE, 256, 0, stream>>>(emb, npos, gpos, ei,
                                            eb1, eb2, mb1, mb2,
                                            wt, sums, counts, E);
    update_kernel<<<G / TE, 256, 0, stream>>>(ub1, ub2, wt, counts, sums, G);
}

// Round 3
// 253.645 us; speedup vs baseline: 8.8663x; 1.2812x over previous
//
#include <hip/hip_runtime.h>

#define HID 128
#define TE  64     // edges (or cells) per block
#define CPB 4      // cells per edge-block (CPB * CAP == TE)
#define CAP 16     // edges per cell (E/G for this problem)
#define LDK 136    // bf16 LDS row stride for 128-wide buffers (272B -> 2-way max, free)
#define LDA 40     // bf16 LDS row stride for 32-wide attr buffer

// bf16 weight region offsets (in bf16 elements) inside wt
#define WT_E1 0
#define WT_E2 4096
#define WT_M1 20480
#define WT_M2 53248
#define WT_U1 69632
#define WT_U2 86016
#define WT_TOTAL 102400

typedef __attribute__((ext_vector_type(8))) short bf16x8;
typedef __attribute__((ext_vector_type(4))) float f32x4;

#define MFMA(a, b, c) __builtin_amdgcn_mfma_f32_16x16x32_bf16(a, b, c, 0, 0, 0)

__device__ __forceinline__ float silu_f(float x) {
    return x * (1.0f / (1.0f + __expf(-x)));
}

// fp32 -> bf16 (round-to-nearest-even), as raw short
__device__ __forceinline__ short f2b(float x) {
    union { float f; unsigned u; } v; v.f = x;
    unsigned r = v.u + 0x7fff + ((v.u >> 16) & 1);
    return (short)(r >> 16);
}

// ---------------------------------------------------------------------------
// Weight conversion: fp32 row-major W[k][n] -> bf16 transposed Wt[n][k]
// ---------------------------------------------------------------------------
extern "C" __global__ void __launch_bounds__(256)
convert_w(const float* __restrict__ ew1, const float* __restrict__ ew2,
          const float* __restrict__ mw1, const float* __restrict__ mw2,
          const float* __restrict__ uw1, const float* __restrict__ uw2,
          short* __restrict__ wt)
{
    int idx = blockIdx.x * 256 + threadIdx.x;
    if (idx >= WT_TOTAL) return;
    int r = idx;
    if (r < 4096) {                               // ew1: [6][128] -> [128][32] K-padded
        int n = r >> 5, k = r & 31;
        wt[idx] = f2b(k < 6 ? ew1[k * HID + n] : 0.0f);
        return;
    }
    r -= 4096;
    if (r < 16384) { int n = r >> 7, k = r & 127; wt[idx] = f2b(ew2[k * HID + n]); return; }
    r -= 16384;
    if (r < 32768) { int n = r >> 8, k = r & 255; wt[idx] = f2b(mw1[k * HID + n]); return; }
    r -= 32768;
    if (r < 16384) { int n = r >> 7, k = r & 127; wt[idx] = f2b(mw2[k * HID + n]); return; }
    r -= 16384;
    if (r < 16384) { int n = r >> 7, k = r & 127; wt[idx] = f2b(uw1[k * HID + n]); return; }
    r -= 16384;
    { int n = r >> 7, k = r & 127; wt[idx] = f2b(uw2[k * HID + n]); return; }
}

// ---------------------------------------------------------------------------
// Binning: group edge ids by destination cell. cnt must be pre-zeroed.
// ---------------------------------------------------------------------------
extern "C" __global__ void __launch_bounds__(256)
bin_kernel(const int* __restrict__ ei, int* __restrict__ cnt,
           int* __restrict__ bin, int E)
{
    int e = blockIdx.x * 256 + threadIdx.x;
    if (e >= E) return;
    int j = ei[E + e];
    int slot = atomicAdd(&cnt[j], 1);
    if (slot < CAP) bin[(size_t)j * CAP + slot] = e;
}

// ---------------------------------------------------------------------------
// GEMM building blocks (A = activations in LDS, B = bf16 transposed weights).
//  A-frag: lane holds row (lane&15), k-chunk (lane>>4)*8
//  B-frag: lane holds col (lane&15) (= row of Wt), k-chunk (lane>>4)*8
//  C-frag: col = lane&15, row = (lane>>4)*4 + reg
// ---------------------------------------------------------------------------
__device__ __forceinline__ void gemm_tile(f32x4 acc[4][2],
                                          const short* __restrict__ sA, int ldsa, int kA0,
                                          const short* __restrict__ wtB, int ldb, int kB0,
                                          int ksteps, int q, int h, int nb)
{
    for (int ks = 0; ks < ksteps; ++ks) {
        int kb = kB0 + ks * 32 + h * 8;
        bf16x8 b0 = *(const bf16x8*)(wtB + (size_t)(nb + q) * ldb + kb);
        bf16x8 b1 = *(const bf16x8*)(wtB + (size_t)(nb + 16 + q) * ldb + kb);
        int ka = kA0 + ks * 32 + h * 8;
        #pragma unroll
        for (int m = 0; m < 4; ++m) {
            bf16x8 a = *(const bf16x8*)(sA + (m * 16 + q) * ldsa + ka);
            acc[m][0] = MFMA(a, b0, acc[m][0]);
            acc[m][1] = MFMA(a, b1, acc[m][1]);
        }
    }
}

__device__ __forceinline__ void epi_lds(f32x4 acc[4][2], const float* __restrict__ bias,
                                        short* __restrict__ sOut, int q, int h, int nb,
                                        bool act)
{
    #pragma unroll
    for (int nf = 0; nf < 2; ++nf) {
        int n = nb + nf * 16 + q;
        float bb = bias[n];
        #pragma unroll
        for (int m = 0; m < 4; ++m) {
            f32x4 v = acc[m][nf];
            #pragma unroll
            for (int r = 0; r < 4; ++r) {
                float z = v[r] + bb;
                if (act) z = silu_f(z);
                sOut[(m * 16 + h * 4 + r) * LDK + n] = f2b(z);
            }
        }
    }
}

__device__ __forceinline__ void zero_acc(f32x4 acc[4][2]) {
    #pragma unroll
    for (int m = 0; m < 4; ++m)
        #pragma unroll
        for (int nf = 0; nf < 2; ++nf)
            acc[m][nf] = (f32x4)(0.0f);
}

// ---------------------------------------------------------------------------
// Edge kernel: block = 4 cells x 16 binned edges. Segment-mean is an
// intra-block reduction -> regular stores. NO fp32 atomics.
// ---------------------------------------------------------------------------
extern "C" __global__ void __launch_bounds__(256, 3)
edge_kernel(const float* __restrict__ emb,
            const float* __restrict__ npos,
            const float* __restrict__ gpos,
            const int* __restrict__ ei,
            const float* __restrict__ eb1, const float* __restrict__ eb2,
            const float* __restrict__ mb1, const float* __restrict__ mb2,
            const short* __restrict__ wt,
            const int* __restrict__ cnt,
            const int* __restrict__ bin,
            float* __restrict__ mean_out,   // [G,HID] (d_out)
            int E)
{
    __shared__ short s_e[TE * LDK];   // gathered node embedding (bf16)
    __shared__ short s_x[TE * LDK];   // h1 / h2 ping
    __shared__ short s_y[TE * LDK];   // attr (overlaid) then pos_emb

    const int t  = threadIdx.x;
    const int c0 = blockIdx.x * CPB;

    // ---- stage 0a: attr rows (K-padded to 32, bf16)
    if (t < TE) {
        int cell = c0 + (t >> 4);
        int eid  = bin[(size_t)c0 * CAP + t];
        int i    = ei[eid];
        const float* np = npos + (size_t)i * 3;
        const float* gp = gpos + (size_t)cell * 3;
        short* arow = s_y + t * LDA;
        arow[0] = f2b(np[0]); arow[1] = f2b(np[1]); arow[2] = f2b(np[2]);
        arow[3] = f2b(gp[0]); arow[4] = f2b(gp[1]); arow[5] = f2b(gp[2]);
        #pragma unroll
        for (int k = 6; k < 32; ++k) arow[k] = 0;
    }

    // ---- stage 0b: gather node embedding -> bf16 LDS (4 threads per edge)
    {
        int e    = t >> 2;
        int part = t & 3;
        int i    = ei[bin[(size_t)c0 * CAP + e]];    // L1-hot re-read
        const float4* src = (const float4*)(emb + (size_t)i * HID + part * 32);
        short* dst = s_e + e * LDK + part * 32;
        #pragma unroll
        for (int qd = 0; qd < 8; ++qd) {
            float4 v = src[qd];
            short4 b;
            b.x = f2b(v.x); b.y = f2b(v.y); b.z = f2b(v.z); b.w = f2b(v.w);
            *(short4*)(dst + qd * 4) = b;
        }
    }
    __syncthreads();

    const int lane = t & 63;
    const int q = lane & 15;
    const int h = lane >> 4;
    const int nb = (t >> 6) * 32;

    f32x4 acc[4][2];

    // ---- L1: h1 = silu(attr @ ew1 + eb1) -> s_x   (K=32 padded)
    zero_acc(acc);
    gemm_tile(acc, s_y, LDA, 0, wt + WT_E1, 32, 0, 1, q, h, nb);
    epi_lds(acc, eb1, s_x, q, h, nb, true);
    __syncthreads();

    // ---- L2: pos = h1 @ ew2 + eb2 -> s_y
    zero_acc(acc);
    gemm_tile(acc, s_x, LDK, 0, wt + WT_E2, HID, 0, 4, q, h, nb);
    epi_lds(acc, eb2, s_y, q, h, nb, false);
    __syncthreads();

    // ---- L3: h2 = silu(emb @ mw1[:128] + pos @ mw1[128:] + mb1) -> s_x
    zero_acc(acc);
    gemm_tile(acc, s_e, LDK, 0, wt + WT_M1, 256, 0,   4, q, h, nb);
    gemm_tile(acc, s_y, LDK, 0, wt + WT_M1, 256, 128, 4, q, h, nb);
    epi_lds(acc, mb1, s_x, q, h, nb, true);
    __syncthreads();

    // ---- L4: message = h2 @ mw2; segment-mean over each cell's 16 rows
    zero_acc(acc);
    gemm_tile(acc, s_x, LDK, 0, wt + WT_M2, HID, 0, 4, q, h, nb);

    float inv[CPB];
    #pragma unroll
    for (int m = 0; m < CPB; ++m) {
        int c = cnt[c0 + m];
        inv[m] = 1.0f / (float)(c > 0 ? c : 1);
    }

    #pragma unroll
    for (int m = 0; m < CPB; ++m) {
        #pragma unroll
        for (int nf = 0; nf < 2; ++nf) {
            f32x4 v = acc[m][nf];
            float s = (v[0] + v[1]) + (v[2] + v[3]);   // sum over 4 local rows
            s += __shfl_xor(s, 16);                    // sum across h-groups
            s += __shfl_xor(s, 32);
            if (h == 0) {
                int n = nb + nf * 16 + q;
                mean_out[(size_t)(c0 + m) * HID + n] = s * inv[m] + mb2[n];
            }
        }
    }
}

// ---------------------------------------------------------------------------
// Update kernel: 64 cells/block; mean -> silu MLP -> out (in-place)
// ---------------------------------------------------------------------------
extern "C" __global__ void __launch_bounds__(256, 3)
update_kernel(const float* __restrict__ ub1, const float* __restrict__ ub2,
              const short* __restrict__ wt,
              float* __restrict__ out, int G)
{
    __shared__ short s_x[TE * LDK];
    __shared__ short s_y[TE * LDK];

    const int t  = threadIdx.x;
    const int c0 = blockIdx.x * TE;

    // stage: mean (fp32) -> bf16 LDS
    {
        int c    = t >> 2;
        int part = t & 3;
        const float4* src = (const float4*)(out + (size_t)(c0 + c) * HID + part * 32);
        short* dst = s_x + c * LDK + part * 32;
        #pragma unroll
        for (int qd = 0; qd < 8; ++qd) {
            float4 v = src[qd];
            short4 b;
            b.x = f2b(v.x); b.y = f2b(v.y); b.z = f2b(v.z); b.w = f2b(v.w);
            *(short4*)(dst + qd * 4) = b;
        }
    }
    __syncthreads();

    const int lane = t & 63;
    const int q = lane & 15;
    const int h = lane >> 4;
    const int nb = (t >> 6) * 32;

    f32x4 acc[4][2];

    // u1: silu(mean @ uw1 + ub1) -> s_y
    zero_acc(acc);
    gemm_tile(acc, s_x, LDK, 0, wt + WT_U1, HID, 0, 4, q, h, nb);
    epi_lds(acc, ub1, s_y, q, h, nb, true);
    __syncthreads();

    // u2: out = h @ uw2 + ub2
    zero_acc(acc);
    gemm_tile(acc, s_y, LDK, 0, wt + WT_U2, HID, 0, 4, q, h, nb);
    #pragma unroll
    for (int nf = 0; nf < 2; ++nf) {
        int n = nb + nf * 16 + q;
        float bb = ub2[n];
        #pragma unroll
        for (int m = 0; m < 4; ++m) {
            f32x4 v = acc[m][nf];
            #pragma unroll
            for (int r = 0; r < 4; ++r) {
                int row = c0 + m * 16 + h * 4 + r;
                out[(size_t)row * HID + n] = v[r] + bb;
            }
        }
    }
}

// ---------------------------------------------------------------------------
extern "C" void kernel_launch(void* const* d_in, const int* in_sizes, int n_in,
                              void* d_out, int out_size, void* d_ws, size_t ws_size,
                              hipStream_t stream)
{
    const float* emb  = (const float*)d_in[0];
    const float* npos = (const float*)d_in[1];
    const float* gpos = (const float*)d_in[2];
    const int*   ei   = (const int*)d_in[3];
    const float* ew1  = (const float*)d_in[4];
    const float* eb1  = (const float*)d_in[5];
    const float* ew2  = (const float*)d_in[6];
    const float* eb2  = (const float*)d_in[7];
    const float* mw1  = (const float*)d_in[8];
    const float* mb1  = (const float*)d_in[9];
    const float* mw2  = (const float*)d_in[10];
    const float* mb2  = (const float*)d_in[11];
    const float* uw1  = (const float*)d_in[12];
    const float* ub1  = (const float*)d_in[13];
    const float* uw2  = (const float*)d_in[14];
    const float* ub2  = (const float*)d_in[15];

    const int E = in_sizes[3] / 2;
    const int G = in_sizes[2] / 3;

    // workspace layout: cnt int[G] | bin int[G*CAP] | wt bf16[WT_TOTAL]
    int*   cnt = (int*)d_ws;
    int*   bin = (int*)((char*)d_ws + (size_t)G * 4);
    short* wt  = (short*)((char*)d_ws + (size_t)G * 4 + (size_t)G * CAP * 4);

    float* mean_buf = (float*)d_out;   // [G, HID], overwritten in place by update

    // zero cnt + binlist (contiguous)
    hipMemsetAsync(d_ws, 0, (size_t)G * (4 + CAP * 4), stream);

    convert_w<<<(WT_TOTAL + 255) / 256, 256, 0, stream>>>(ew1, ew2, mw1, mw2, uw1, uw2, wt);
    bin_kernel<<<(E + 255) / 256, 256, 0, stream>>>(ei, cnt, bin, E);
    edge_kernel<<<G / CPB, 256, 0, stream>>>(emb, npos, gpos, ei,
                                             eb1, eb2, mb1, mb2,
                                             wt, cnt, bin, mean_buf, E);
    update_kernel<<<G / TE, 256, 0, stream>>>(ub1, ub2, wt, mean_buf, G);
}